// Round 1
// baseline (1354.970 us; speedup 1.0000x reference)
//
#include <hip/hip_runtime.h>

#define EPSF 1e-9f

// Block = 256 threads = (o, p) with o = tid>>4, p = tid&15 (p = pr*4+pc).
// One block per output position n = (b, h', w'). Votes v[i, o_self, p_self]
// live in 144 VGPRs per thread; rr'/zz and the pose patch live in LDS.
__global__ __launch_bounds__(256, 2)
void capsule_em_kernel(const float* __restrict__ pose_in,   // [8,14,14,256]
                       const float* __restrict__ act_in,    // [8,14,14,16]
                       const float* __restrict__ w,         // [144,16,4,4]
                       const float* __restrict__ beta_v,    // [16]
                       const float* __restrict__ beta_a,    // [16]
                       float* __restrict__ out)             // pose 294912 | act 18432
{
    constexpr int I = 144;
    constexpr int RRS = 17;                   // padded row stride (conflict-free)
    __shared__ float s_pose[I * 16];          // pose patch [i][16]
    __shared__ float s_rr[I * RRS];           // rr' (then zz) [i][o], padded
    __shared__ float s_iact[I];

    const int tid = threadIdx.x;
    const int o   = tid >> 4;
    const int p   = tid & 15;
    const int pr  = p >> 2;
    const int pc  = p & 3;

    const int n    = blockIdx.x;
    const int b    = n / 144;
    const int rem  = n - b * 144;
    const int hp   = rem / 12;
    const int wpos = rem - hp * 12;

    // ---- stage pose patch (9 rows x 256 contiguous floats) + i_act ----
    #pragma unroll
    for (int pk = 0; pk < 9; ++pk) {
        const int ki = pk / 3, kj = pk - ki * 3;
        const int base = ((b * 14 + hp + ki) * 14 + (wpos + kj)) * 256;
        s_pose[pk * 256 + tid] = pose_in[base + tid];
    }
    if (tid < I) {
        const int pk = tid >> 4, ic = tid & 15;
        const int ki = pk / 3, kj = pk - ki * 3;
        s_iact[tid] = act_in[((b * 14 + hp + ki) * 14 + (wpos + kj)) * 16 + ic];
    }
    __syncthreads();

    // ---- votes: v[i] = sum_q pose[i, pr, q] * w[i, o, q, pc] ----
    float v[I];
    #pragma unroll
    for (int i = 0; i < I; ++i) {
        const float* pb = &s_pose[i * 16 + pr * 4];       // contiguous 16B
        const float* wb = &w[i * 256 + o * 16 + pc];      // column pc, stride 4
        v[i] = pb[0] * wb[0] + pb[1] * wb[4] + pb[2] * wb[8] + pb[3] * wb[12];
    }

    // ---- init rr' = i_act / O ----
    for (int idx = tid; idx < I * 16; idx += 256) {
        const int i = idx >> 4, oo = idx & 15;
        s_rr[i * RRS + oo] = s_iact[i] * (1.0f / 16.0f);
    }
    __syncthreads();

    const float bv = beta_v[o];
    const float ba = beta_a[o];

    float mean = 0.0f, o_act = 0.0f;

    for (int it = 0; it < 3; ++it) {
        // ---------------- M-step ----------------
        float accS = 0.0f, acc1 = 0.0f, acc2 = 0.0f;
        #pragma unroll
        for (int i = 0; i < I; ++i) {
            const float r = s_rr[i * RRS + o];   // broadcast across 16 p-lanes
            const float t = r * v[i];
            accS += r;
            acc1 += t;
            acc2 += t * v[i];
        }
        const float inv = 1.0f / (accS + EPSF);
        mean = acc1 * inv;
        float var = (acc2 - 2.0f * mean * acc1 + mean * mean * accS) * inv;
        var = fmaxf(var, 0.0f);
        const float sigma = sqrtf(var);

        float slog = __logf(sigma + EPSF);       // sum_p log(sigma+eps), butterfly
        slog += __shfl_xor(slog, 1);
        slog += __shfl_xor(slog, 2);
        slog += __shfl_xor(slog, 4);
        slog += __shfl_xor(slog, 8);

        const float cost_sum = accS * (16.0f * bv + slog);
        const float inv_temp = 1.0f + (float)it;
        const float z = inv_temp * (ba - cost_sum);
        o_act = 1.0f / (1.0f + __expf(-z));

        // ---------------- E-step (skipped on last iter) ----------------
        if (it < 2) {
            const float inv2v = 1.0f / (2.0f * sigma * sigma + EPSF);
            const float Lo = __logf(o_act + EPSF) - slog;
            __syncthreads();                     // all M-step rr reads done
            #pragma unroll
            for (int i = 0; i < I; ++i) {
                const float d = v[i] - mean;
                float q = d * d * inv2v;
                q += __shfl_xor(q, 1);
                q += __shfl_xor(q, 2);
                q += __shfl_xor(q, 4);
                q += __shfl_xor(q, 8);
                if (p == 0) s_rr[i * RRS + o] = Lo - q;   // zz[i][o]
            }
            __syncthreads();
            // softmax over o per i, fold in i_act
            if (tid < I) {
                float zv[16];
                float zmax = -1e30f;
                #pragma unroll
                for (int oo = 0; oo < 16; ++oo) {
                    zv[oo] = s_rr[tid * RRS + oo];
                    zmax = fmaxf(zmax, zv[oo]);
                }
                float se = 0.0f;
                #pragma unroll
                for (int oo = 0; oo < 16; ++oo) {
                    zv[oo] = __expf(zv[oo] - zmax);
                    se += zv[oo];
                }
                const float sc = s_iact[tid] / se;
                #pragma unroll
                for (int oo = 0; oo < 16; ++oo)
                    s_rr[tid * RRS + oo] = zv[oo] * sc;   // rr' for next M-step
            }
            __syncthreads();
        }
    }

    // ---- outputs: pose (last o_mean), activation (last o_act) ----
    out[n * 256 + o * 16 + p] = mean;                     // coalesced
    if (p == 0) out[8 * 12 * 12 * 256 + n * 16 + o] = o_act;
}

extern "C" void kernel_launch(void* const* d_in, const int* in_sizes, int n_in,
                              void* d_out, int out_size, void* d_ws, size_t ws_size,
                              hipStream_t stream) {
    const float* pose = (const float*)d_in[0];
    const float* act  = (const float*)d_in[1];
    const float* w    = (const float*)d_in[2];
    const float* bv   = (const float*)d_in[3];
    const float* ba   = (const float*)d_in[4];
    float* out = (float*)d_out;
    capsule_em_kernel<<<dim3(8 * 12 * 12), dim3(256), 0, stream>>>(pose, act, w, bv, ba, out);
}

// Round 2
// 191.367 us; speedup vs baseline: 7.0805x; 7.0805x over previous
//
#include <hip/hip_runtime.h>

#define EPSF 1e-9f

constexpr int I   = 144;   // 9 * 16 input capsules
constexpr int CH  = 4;     // i-chunks across threads
constexpr int IC  = I / CH;// 36 votes per thread (stays in VGPRs)
constexpr int RRS = 17;    // padded rr row stride

// Block = 1024 threads = (c, o, p): c = tid>>8 (i-chunk), o = (tid>>4)&15,
// p = tid&15. One block per output position. v[36] per thread in registers;
// cross-chunk sums reduced via s_red; p-sums via __shfl_xor (within wave:
// a wave is 4 o-groups x 16 p, so masks 1/2/4/8 stay inside a 16-lane group).
__global__ __launch_bounds__(1024, 4)
void capsule_em_kernel(const float* __restrict__ pose_in,   // [8,14,14,256]
                       const float* __restrict__ act_in,    // [8,14,14,16]
                       const float* __restrict__ w,         // [144,16,4,4]
                       const float* __restrict__ beta_v,    // [16]
                       const float* __restrict__ beta_a,    // [16]
                       float* __restrict__ out)             // pose | act
{
    __shared__ float s_pose[I * 16];          // 9.0 KB
    __shared__ float s_rr[I * RRS];           // 9.6 KB  (rr', then zz)
    __shared__ float s_iact[I];               // 0.6 KB
    __shared__ float s_red[3][CH * 256];      // 12 KB   (accS/acc1/acc2 partials)

    const int tid = threadIdx.x;
    const int c   = tid >> 8;
    const int r8  = tid & 255;
    const int o   = r8 >> 4;
    const int p   = r8 & 15;
    const int pr  = p >> 2;
    const int pc  = p & 3;
    const int i0  = c * IC;

    const int n   = blockIdx.x;
    const int b   = n / 144;
    const int rem = n - b * 144;
    const int hp  = rem / 12;
    const int wp  = rem - hp * 12;

    // ---- stage pose patch (9 x 256 floats) + i_act ----
    for (int idx = tid; idx < 9 * 256; idx += 1024) {
        const int pk = idx >> 8, off = idx & 255;
        const int ki = pk / 3, kj = pk - ki * 3;
        s_pose[idx] = pose_in[((b * 14 + hp + ki) * 14 + (wp + kj)) * 256 + off];
    }
    if (tid < I) {
        const int pk = tid >> 4, ic = tid & 15;
        const int ki = pk / 3, kj = pk - ki * 3;
        s_iact[tid] = act_in[((b * 14 + hp + ki) * 14 + (wp + kj)) * 16 + ic];
    }
    __syncthreads();

    // ---- init rr' = i_act / O ----
    for (int idx = tid; idx < I * 16; idx += 1024) {
        const int i = idx >> 4, oo = idx & 15;
        s_rr[i * RRS + oo] = s_iact[i] * (1.0f / 16.0f);
    }

    // ---- votes for my 36 i's: v[ii] = sum_q pose[i,pr,q] * w[i,o,q,pc] ----
    float v[IC];
    #pragma unroll
    for (int ii = 0; ii < IC; ++ii) {
        const int i = i0 + ii;
        const float4 pv = *reinterpret_cast<const float4*>(&s_pose[i * 16 + pr * 4]);
        const float* wb = &w[i * 256 + o * 16 + pc];
        v[ii] = pv.x * wb[0] + pv.y * wb[4] + pv.z * wb[8] + pv.w * wb[12];
    }
    __syncthreads();   // rr' visible; M-step may read

    const float bv = beta_v[o];
    const float ba = beta_a[o];

    float mean = 0.0f, o_act = 0.0f;

    for (int it = 0; it < 3; ++it) {
        // ---------------- M-step: per-chunk partials ----------------
        float accS = 0.0f, acc1 = 0.0f, acc2 = 0.0f;
        #pragma unroll
        for (int ii = 0; ii < IC; ++ii) {
            const float r = s_rr[(i0 + ii) * RRS + o];
            const float t = r * v[ii];
            accS += r;
            acc1 += t;
            acc2 += t * v[ii];
        }
        s_red[0][tid] = accS;
        s_red[1][tid] = acc1;
        s_red[2][tid] = acc2;
        __syncthreads();   // also: all rr reads of this M-step are done

        accS = acc1 = acc2 = 0.0f;
        #pragma unroll
        for (int cc = 0; cc < CH; ++cc) {
            accS += s_red[0][cc * 256 + r8];
            acc1 += s_red[1][cc * 256 + r8];
            acc2 += s_red[2][cc * 256 + r8];
        }

        const float inv = 1.0f / (accS + EPSF);
        mean = acc1 * inv;
        float var = (acc2 - 2.0f * mean * acc1 + mean * mean * accS) * inv;
        var = fmaxf(var, 0.0f);
        const float sigma = sqrtf(var);

        float slog = __logf(sigma + EPSF);      // sum over p via butterfly
        slog += __shfl_xor(slog, 1);
        slog += __shfl_xor(slog, 2);
        slog += __shfl_xor(slog, 4);
        slog += __shfl_xor(slog, 8);

        const float cost_sum = accS * (16.0f * bv + slog);
        const float inv_temp = 1.0f + (float)it;
        o_act = 1.0f / (1.0f + __expf(-inv_temp * (ba - cost_sum)));

        // ---------------- E-step (skip on last iter) ----------------
        if (it < 2) {
            const float inv2v = 1.0f / (2.0f * sigma * sigma + EPSF);
            const float Lo = __logf(o_act + EPSF) - slog;
            #pragma unroll
            for (int ii = 0; ii < IC; ++ii) {
                const float d = v[ii] - mean;
                float q = d * d * inv2v;
                q += __shfl_xor(q, 1);
                q += __shfl_xor(q, 2);
                q += __shfl_xor(q, 4);
                q += __shfl_xor(q, 8);
                if (p == 0) s_rr[(i0 + ii) * RRS + o] = Lo - q;   // zz[i][o]
            }
            __syncthreads();
            // softmax over o per i, fold in i_act -> rr' for next M-step
            if (tid < I) {
                float zv[16];
                float zmax = -1e30f;
                #pragma unroll
                for (int oo = 0; oo < 16; ++oo) {
                    zv[oo] = s_rr[tid * RRS + oo];
                    zmax = fmaxf(zmax, zv[oo]);
                }
                float se = 0.0f;
                #pragma unroll
                for (int oo = 0; oo < 16; ++oo) {
                    zv[oo] = __expf(zv[oo] - zmax);
                    se += zv[oo];
                }
                const float sc = s_iact[tid] / se;
                #pragma unroll
                for (int oo = 0; oo < 16; ++oo)
                    s_rr[tid * RRS + oo] = zv[oo] * sc;
            }
            __syncthreads();
        }
    }

    // ---- outputs ----
    if (c == 0) {
        out[n * 256 + o * 16 + p] = mean;                       // pose, coalesced
        if (p == 0) out[8 * 12 * 12 * 256 + n * 16 + o] = o_act; // activation
    }
}

extern "C" void kernel_launch(void* const* d_in, const int* in_sizes, int n_in,
                              void* d_out, int out_size, void* d_ws, size_t ws_size,
                              hipStream_t stream) {
    const float* pose = (const float*)d_in[0];
    const float* act  = (const float*)d_in[1];
    const float* w    = (const float*)d_in[2];
    const float* bv   = (const float*)d_in[3];
    const float* ba   = (const float*)d_in[4];
    float* out = (float*)d_out;
    capsule_em_kernel<<<dim3(8 * 12 * 12), dim3(1024), 0, stream>>>(pose, act, w, bv, ba, out);
}